// Round 18
// baseline (250.410 us; speedup 1.0000x reference)
//
#include <hip/hip_runtime.h>
#include <hip/hip_bf16.h>
#include <hip/hip_fp16.h>
#include <cstdint>

// Dims
constexpr int B_ = 4, H_ = 16, S_ = 1024, D_ = 1024, DK_ = 64;

typedef __bf16 bf16x8 __attribute__((ext_vector_type(8)));
typedef float f32x4 __attribute__((ext_vector_type(4)));
typedef __fp16 fp16x2 __attribute__((ext_vector_type(2)));
#define MFMA16(a, b, c) __builtin_amdgcn_mfma_f32_16x16x32_bf16(a, b, c, 0, 0, 0)

static __device__ inline unsigned short f2bf(float f) {
  __hip_bfloat16 h = __float2bfloat16(f);
  return *reinterpret_cast<unsigned short*>(&h);
}
static __device__ inline unsigned packbf(float lo, float hi) {
  return ((unsigned)f2bf(hi) << 16) | (unsigned)f2bf(lo);
}
static __device__ inline unsigned pack_f16(float x, float y) {
  fp16x2 p = __builtin_amdgcn_cvt_pkrtz(x, y);  // 1 instruction
  return *reinterpret_cast<unsigned*>(&p);
}
static __device__ inline float f16lo(unsigned u) {
  unsigned short s = (unsigned short)(u & 0xffff);
  return __half2float(*reinterpret_cast<__half*>(&s));
}
static __device__ inline float f16hi(unsigned u) {
  unsigned short s = (unsigned short)(u >> 16);
  return __half2float(*reinterpret_cast<__half*>(&s));
}

// ---------------------------------------------------------------------------
// f32 -> bf16 conversion for the 4 weight matrices only (q/k/v are converted
// in-flight inside k_proj3's A staging now). 4096 blocks.
// ---------------------------------------------------------------------------
__global__ __launch_bounds__(256) void k_cvt4(const float* __restrict__ x0,
                                              const float* __restrict__ x1,
                                              const float* __restrict__ x2,
                                              const float* __restrict__ x3,
                                              __hip_bfloat16* __restrict__ y0,
                                              __hip_bfloat16* __restrict__ y1,
                                              __hip_bfloat16* __restrict__ y2,
                                              __hip_bfloat16* __restrict__ y3) {
  const int sel = blockIdx.x >> 10;
  const int i = (blockIdx.x & 1023) * 256 + threadIdx.x;
  const float* x = sel == 0 ? x0 : (sel == 1 ? x1 : (sel == 2 ? x2 : x3));
  __hip_bfloat16* y = sel == 0 ? y0 : (sel == 1 ? y1 : (sel == 2 ? y2 : y3));
  const float4 v = reinterpret_cast<const float4*>(x)[i];
  ushort4 o;
  o.x = f2bf(v.x); o.y = f2bf(v.y); o.z = f2bf(v.z); o.w = f2bf(v.w);
  *reinterpret_cast<ushort4*>(&y[(size_t)i * 4]) = o;
}

// ---------------------------------------------------------------------------
// Fused Q/K/V projections reading f32 activations DIRECTLY (A staged via
// reg-cvt: 2x float4 load -> 8 bf16 pack -> 16B ds_write; 2-way LDS conflict
// = free). B (weights) pre-converted bf16 via global_load_lds.
// blockIdx.z selects tensor; z==2 (V) writes transposed. 1536 blocks.
// ---------------------------------------------------------------------------
__global__ __launch_bounds__(256) void k_proj3(const float* __restrict__ xq,
                                               const float* __restrict__ xk,
                                               const float* __restrict__ xv,
                                               const __hip_bfloat16* __restrict__ wq,
                                               const __hip_bfloat16* __restrict__ wk,
                                               const __hip_bfloat16* __restrict__ wv,
                                               __hip_bfloat16* __restrict__ Qh,
                                               __hip_bfloat16* __restrict__ Kh,
                                               __hip_bfloat16* __restrict__ VT) {
  __shared__ __hip_bfloat16 Als[128 * 64];
  __shared__ __hip_bfloat16 Bls[64 * 64];
  const int z = blockIdx.z;
  const float* A = z == 0 ? xq : (z == 1 ? xk : xv);
  const __hip_bfloat16* Bw = z == 0 ? wq : (z == 1 ? wk : wv);
  __hip_bfloat16* Yb = z == 0 ? Qh : (z == 1 ? Kh : VT);
  const int rt = blockIdx.x, ct = blockIdx.y;
  const int tid = threadIdx.x;
  const int lane = tid & 63;
  const int l15 = lane & 15, g = lane >> 4;
  const int w = tid >> 6;
  const int wr = w >> 1, wc = w & 1;
  f32x4 acc[4][2] = {};

  for (int k0 = 0; k0 < D_; k0 += 64) {
    // A: f32 -> bf16 reg-staged (4 slots per thread)
#pragma unroll
    for (int q = 0; q < 4; ++q) {
      const int slot = q * 256 + tid;
      const int r = slot >> 3, p = slot & 7;
      const int lc = p ^ (r & 7);
      const float* src = A + (size_t)(rt * 128 + r) * D_ + k0 + lc * 8;
      const float4 a0 = *reinterpret_cast<const float4*>(src);
      const float4 a1 = *reinterpret_cast<const float4*>(src + 4);
      uint4 pk;
      pk.x = packbf(a0.x, a0.y);
      pk.y = packbf(a0.z, a0.w);
      pk.z = packbf(a1.x, a1.y);
      pk.w = packbf(a1.z, a1.w);
      *reinterpret_cast<uint4*>(&Als[slot * 8]) = pk;
    }
    // B: bf16 weights via global_load_lds
#pragma unroll
    for (int q = 0; q < 2; ++q) {
      const int slot0 = q * 256 + (tid & 192);
      const int slot = slot0 + lane;
      const int r = slot >> 3, p = slot & 7;
      const int lc = p ^ (r & 7);
      const __hip_bfloat16* src = Bw + (size_t)(ct * 64 + r) * D_ + k0 + lc * 8;
      __builtin_amdgcn_global_load_lds(
          (const __attribute__((address_space(1))) unsigned int*)src,
          (__attribute__((address_space(3))) unsigned int*)&Bls[slot0 * 8], 16, 0, 0);
    }
    __syncthreads();
#pragma unroll
    for (int ks = 0; ks < 2; ++ks) {
      bf16x8 bfr[2];
#pragma unroll
      for (int cf = 0; cf < 2; ++cf) {
        const int r = wc * 32 + cf * 16 + l15;
        const int p = (ks * 4 + g) ^ (r & 7);
        bfr[cf] = *reinterpret_cast<const bf16x8*>(&Bls[(r * 8 + p) * 8]);
      }
#pragma unroll
      for (int fi = 0; fi < 4; ++fi) {
        const int r = wr * 64 + fi * 16 + l15;
        const int p = (ks * 4 + g) ^ (r & 7);
        const bf16x8 af = *reinterpret_cast<const bf16x8*>(&Als[(r * 8 + p) * 8]);
        acc[fi][0] = MFMA16(af, bfr[0], acc[fi][0]);
        acc[fi][1] = MFMA16(af, bfr[1], acc[fi][1]);
      }
    }
    __syncthreads();
  }
#pragma unroll
  for (int fi = 0; fi < 4; ++fi)
#pragma unroll
    for (int cf = 0; cf < 2; ++cf)
#pragma unroll
      for (int r = 0; r < 4; ++r) {
        const int m = rt * 128 + wr * 64 + fi * 16 + 4 * g + r;
        const int t = wc * 32 + cf * 16 + l15;
        const float val = acc[fi][cf][r];
        const int s = m >> 2, b = m & 3;
        if (z != 2) {
          Yb[((size_t)((b * H_ + ct) * S_ + s)) * DK_ + t] = __float2bfloat16(val);
        } else {
          Yb[((size_t)((b * H_ + ct) * DK_ + t)) * S_ + s] = __float2bfloat16(val);
        }
      }
}

// ---------------------------------------------------------------------------
// Wo GEMM + residual (f32 out). A=Ob bf16, B=wob bf16, both global_load_lds.
// ---------------------------------------------------------------------------
__global__ __launch_bounds__(256) void k_wo(const __hip_bfloat16* __restrict__ A,
                                            const __hip_bfloat16* __restrict__ Bw,
                                            const float* __restrict__ resid,
                                            float* __restrict__ Yf) {
  __shared__ __hip_bfloat16 Als[128 * 64];
  __shared__ __hip_bfloat16 Bls[64 * 64];
  const int rt = blockIdx.x, ct = blockIdx.y;
  const int tid = threadIdx.x;
  const int lane = tid & 63;
  const int l15 = lane & 15, g = lane >> 4;
  const int w = tid >> 6;
  const int wr = w >> 1, wc = w & 1;
  f32x4 acc[4][2] = {};
  for (int k0 = 0; k0 < D_; k0 += 64) {
#pragma unroll
    for (int q = 0; q < 4; ++q) {
      const int slot0 = q * 256 + (tid & 192);
      const int slot = slot0 + lane;
      const int r = slot >> 3, p = slot & 7;
      const int lc = p ^ (r & 7);
      const __hip_bfloat16* src = A + (size_t)(rt * 128 + r) * D_ + k0 + lc * 8;
      __builtin_amdgcn_global_load_lds(
          (const __attribute__((address_space(1))) unsigned int*)src,
          (__attribute__((address_space(3))) unsigned int*)&Als[slot0 * 8], 16, 0, 0);
    }
#pragma unroll
    for (int q = 0; q < 2; ++q) {
      const int slot0 = q * 256 + (tid & 192);
      const int slot = slot0 + lane;
      const int r = slot >> 3, p = slot & 7;
      const int lc = p ^ (r & 7);
      const __hip_bfloat16* src = Bw + (size_t)(ct * 64 + r) * D_ + k0 + lc * 8;
      __builtin_amdgcn_global_load_lds(
          (const __attribute__((address_space(1))) unsigned int*)src,
          (__attribute__((address_space(3))) unsigned int*)&Bls[slot0 * 8], 16, 0, 0);
    }
    __syncthreads();
#pragma unroll
    for (int ks = 0; ks < 2; ++ks) {
      bf16x8 bfr[2];
#pragma unroll
      for (int cf = 0; cf < 2; ++cf) {
        const int r = wc * 32 + cf * 16 + l15;
        const int p = (ks * 4 + g) ^ (r & 7);
        bfr[cf] = *reinterpret_cast<const bf16x8*>(&Bls[(r * 8 + p) * 8]);
      }
#pragma unroll
      for (int fi = 0; fi < 4; ++fi) {
        const int r = wr * 64 + fi * 16 + l15;
        const int p = (ks * 4 + g) ^ (r & 7);
        const bf16x8 af = *reinterpret_cast<const bf16x8*>(&Als[(r * 8 + p) * 8]);
        acc[fi][0] = MFMA16(af, bfr[0], acc[fi][0]);
        acc[fi][1] = MFMA16(af, bfr[1], acc[fi][1]);
      }
    }
    __syncthreads();
  }
#pragma unroll
  for (int fi = 0; fi < 4; ++fi)
#pragma unroll
    for (int cf = 0; cf < 2; ++cf)
#pragma unroll
      for (int r = 0; r < 4; ++r) {
        const int m = rt * 128 + wr * 64 + fi * 16 + 4 * g + r;
        const int t = wc * 32 + cf * 16 + l15;
        const int b = m >> 10, s = m & 1023;
        const int o = ct * 64 + t;
        Yf[(size_t)m * D_ + o] =
            acc[fi][cf][r] + resid[(size_t)(s * B_ + b) * D_ + o];
      }
}

// ---------------------------------------------------------------------------
// Fused attention (R16 best: 165us — nontemporal sph/P streams, no-max
// softmax, deferred normalization, 2-deep K pipeline). UNCHANGED.
// ---------------------------------------------------------------------------
__global__ __launch_bounds__(256, 4) void k_attn(const __hip_bfloat16* __restrict__ Qh,
                                                 const __hip_bfloat16* __restrict__ Kh,
                                                 const __hip_bfloat16* __restrict__ VT,
                                                 const float* __restrict__ sph,
                                                 float* __restrict__ Pout,
                                                 __hip_bfloat16* __restrict__ O) {
  __shared__ unsigned int Plds[16 * 512];  // 32KB logits/P (f16/bf16 pairs)
  __shared__ float invl[16];               // per-row 1/sum for phase 3
  const int tid = threadIdx.x, lane = tid & 63, w = tid >> 6;
  const int l15 = lane & 15, g = lane >> 4;
  const int it = blockIdx.x, bh = blockIdx.y;
  const unsigned sw = (unsigned)((l15 & 7) << 2);
  const int wrow = w * 4;
  constexpr float kScale = 0.125f * 1.44269504088896f;  // /8 then log2(e)

  // ---- phase 1: raw logits; 2-deep K pipeline ----
  {
    const __hip_bfloat16* qp = Qh + ((size_t)bh * S_ + it * 16 + l15) * DK_ + 8 * g;
    const bf16x8 qf0 = *reinterpret_cast<const bf16x8*>(qp);
    const bf16x8 qf1 = *reinterpret_cast<const bf16x8*>(qp + 32);
    const __hip_bfloat16* kb0 =
        Kh + (size_t)bh * S_ * DK_ + (size_t)(w * 256 + l15) * DK_ + 8 * g;
    bf16x8 kra[2], krb[2], krc[2], krd[2];
    kra[0] = *reinterpret_cast<const bf16x8*>(kb0);
    krb[0] = *reinterpret_cast<const bf16x8*>(kb0 + 32);
    krc[0] = *reinterpret_cast<const bf16x8*>(kb0 + 16 * DK_);
    krd[0] = *reinterpret_cast<const bf16x8*>(kb0 + 16 * DK_ + 32);
#pragma unroll
    for (int j = 0; j < 8; ++j) {
      const int cur = j & 1, nxt = cur ^ 1;
      if (j < 7) {
        const __hip_bfloat16* kp = kb0 + (size_t)(j + 1) * 32 * DK_;
        kra[nxt] = *reinterpret_cast<const bf16x8*>(kp);
        krb[nxt] = *reinterpret_cast<const bf16x8*>(kp + 32);
        krc[nxt] = *reinterpret_cast<const bf16x8*>(kp + 16 * DK_);
        krd[nxt] = *reinterpret_cast<const bf16x8*>(kp + 16 * DK_ + 32);
      }
      f32x4 a0 = {0.f, 0.f, 0.f, 0.f};
      f32x4 a1 = {0.f, 0.f, 0.f, 0.f};
      __builtin_amdgcn_s_setprio(1);
      a0 = MFMA16(kra[cur], qf0, a0);
      a0 = MFMA16(krb[cur], qf1, a0);
      a1 = MFMA16(krc[cur], qf0, a1);
      a1 = MFMA16(krd[cur], qf1, a1);
      __builtin_amdgcn_s_setprio(0);
      const int key0 = w * 256 + j * 32;
      uint2 u0, u1;
      u0.x = pack_f16(a0[0] * kScale, a0[1] * kScale);
      u0.y = pack_f16(a0[2] * kScale, a0[3] * kScale);
      u1.x = pack_f16(a1[0] * kScale, a1[1] * kScale);
      u1.y = pack_f16(a1[2] * kScale, a1[3] * kScale);
      const int base0 = l15 * 512 + (key0 >> 1) + 2 * g;  // pair index
      *reinterpret_cast<uint2*>(&Plds[(unsigned)base0 ^ sw]) = u0;
      *reinterpret_cast<uint2*>(&Plds[(unsigned)(base0 + 8) ^ sw]) = u1;
    }
  }
  __syncthreads();

  // ---- phase 2: per-row; no-max softmax, deferred normalization ----
  {
    const f32x4* sbase = reinterpret_cast<const f32x4*>(
        sph + ((size_t)bh << 20) + (((size_t)(it * 16)) << 10));
#pragma unroll
    for (int rr = 0; rr < 4; ++rr) {
      const int row = wrow + rr;
      const unsigned rsw = (unsigned)((row & 7) << 2);
      const int lbase = row * 512;
      uint2 uv[4];
      f32x4 sv[4];
#pragma unroll
      for (int i = 0; i < 4; ++i) {
        sv[i] = __builtin_nontemporal_load(&sbase[(size_t)row * 256 + lane + 64 * i]);
        uv[i] = *reinterpret_cast<uint2*>(
            &Plds[(unsigned)(lbase + 2 * lane + 128 * i) ^ rsw]);
      }
      float va[16];
#pragma unroll
      for (int i = 0; i < 4; ++i) {
        va[4 * i + 0] = f16lo(uv[i].x) * sv[i][0];
        va[4 * i + 1] = f16hi(uv[i].x) * sv[i][1];
        va[4 * i + 2] = f16lo(uv[i].y) * sv[i][2];
        va[4 * i + 3] = f16hi(uv[i].y) * sv[i][3];
      }
#pragma unroll
      for (int i = 0; i < 16; ++i) va[i] = exp2f(fminf(va[i], 60.f));
#pragma unroll
      for (int i = 0; i < 4; ++i) {
        uint2 pb;
        pb.x = packbf(va[4 * i + 0], va[4 * i + 1]);
        pb.y = packbf(va[4 * i + 2], va[4 * i + 3]);
        *reinterpret_cast<uint2*>(
            &Plds[(unsigned)(lbase + 2 * lane + 128 * i) ^ rsw]) = pb;
      }
      const float b0 = va[0] + va[1], b1 = va[2] + va[3], b2 = va[4] + va[5],
                  b3 = va[6] + va[7], b4 = va[8] + va[9], b5 = va[10] + va[11],
                  b6 = va[12] + va[13], b7 = va[14] + va[15];
      float sum = ((b0 + b1) + (b2 + b3)) + ((b4 + b5) + (b6 + b7));
#pragma unroll
      for (int off = 1; off < 64; off <<= 1) sum += __shfl_xor(sum, off);
      const float inv = 1.f / sum;
      if (lane == 0) invl[row] = inv;
      f32x4* po = reinterpret_cast<f32x4*>(Pout + ((size_t)bh << 20) +
                                           (((size_t)(it * 16 + row)) << 10));
#pragma unroll
      for (int i = 0; i < 4; ++i) {
        f32x4 p;
        p[0] = va[4 * i + 0] * inv;
        p[1] = va[4 * i + 1] * inv;
        p[2] = va[4 * i + 2] * inv;
        p[3] = va[4 * i + 3] * inv;
        __builtin_nontemporal_store(p, &po[lane + 64 * i]);
      }
    }
  }
  __syncthreads();

  // ---- phase 3: PV on unnormalized P, batches of 8; scale by invl[row] ----
  {
    const int c0 = w * 16;
    f32x4 o0 = {0.f, 0.f, 0.f, 0.f};
    const __hip_bfloat16* vb =
        VT + (size_t)bh * DK_ * S_ + (size_t)(c0 + l15) * S_ + 8 * g;
#pragma unroll
    for (int kb2 = 0; kb2 < 4; ++kb2) {
      bf16x8 vreg[8];
      bf16x8 preg[8];
#pragma unroll
      for (int u = 0; u < 8; ++u)
        vreg[u] = *reinterpret_cast<const bf16x8*>(vb + kb2 * 256 + u * 32);
#pragma unroll
      for (int u = 0; u < 8; ++u) {
        const int k0 = kb2 * 256 + u * 32;
        preg[u] = *reinterpret_cast<const bf16x8*>(
            &Plds[(unsigned)(l15 * 512 + (k0 >> 1) + 4 * g) ^ sw]);
      }
      __builtin_amdgcn_s_setprio(1);
#pragma unroll
      for (int u = 0; u < 8; ++u) o0 = MFMA16(preg[u], vreg[u], o0);
      __builtin_amdgcn_s_setprio(0);
    }
    const int b = bh >> 4, h = bh & 15;
    const float iv0 = invl[4 * g + 0], iv1 = invl[4 * g + 1];
    const float iv2 = invl[4 * g + 2], iv3 = invl[4 * g + 3];
    const float ivr[4] = {iv0, iv1, iv2, iv3};
#pragma unroll
    for (int r = 0; r < 4; ++r) {
      const int srow = it * 16 + 4 * g + r;
      O[((size_t)(b * S_ + srow)) * D_ + h * DK_ + c0 + l15] =
          __float2bfloat16(o0[r] * ivr[r]);
    }
  }
}

// ---------------------------------------------------------------------------
// LayerNorm over D, write [S,B,D]
// ---------------------------------------------------------------------------
__global__ __launch_bounds__(256) void k_ln(const float* __restrict__ Z,
                                            const float* __restrict__ gamma,
                                            const float* __restrict__ beta,
                                            float* __restrict__ out) {
  const int r = blockIdx.x;  // b*S+s
  const int b = r >> 10, s = r & 1023;
  const int tid = threadIdx.x;
  const float4 z = *reinterpret_cast<const float4*>(Z + (size_t)r * D_ + (tid << 2));
  float sum = z.x + z.y + z.z + z.w;
  float sq = z.x * z.x + z.y * z.y + z.z * z.z + z.w * z.w;
#pragma unroll
  for (int off = 1; off < 64; off <<= 1) {
    sum += __shfl_xor(sum, off);
    sq += __shfl_xor(sq, off);
  }
  __shared__ float rs[4];
  __shared__ float rq[4];
  const int wv = tid >> 6, ln = tid & 63;
  if (ln == 0) { rs[wv] = sum; rq[wv] = sq; }
  __syncthreads();
  const float tsum = rs[0] + rs[1] + rs[2] + rs[3];
  const float tsq = rq[0] + rq[1] + rq[2] + rq[3];
  const float mu = tsum * (1.0f / 1024.0f);
  const float var = tsq * (1.0f / 1024.0f) - mu * mu;
  const float rstd = rsqrtf(var + 1e-6f);
  const float4 gm = *reinterpret_cast<const float4*>(gamma + (tid << 2));
  const float4 bt = *reinterpret_cast<const float4*>(beta + (tid << 2));
  float4 o;
  o.x = (z.x - mu) * rstd * gm.x + bt.x;
  o.y = (z.y - mu) * rstd * gm.y + bt.y;
  o.z = (z.z - mu) * rstd * gm.z + bt.z;
  o.w = (z.w - mu) * rstd * gm.w + bt.w;
  *reinterpret_cast<float4*>(out + (size_t)(s * B_ + b) * D_ + (tid << 2)) = o;
}

extern "C" void kernel_launch(void* const* d_in, const int* in_sizes, int n_in,
                              void* d_out, int out_size, void* d_ws, size_t ws_size,
                              hipStream_t stream) {
  const float* q = (const float*)d_in[0];
  const float* k = (const float*)d_in[1];
  const float* v = (const float*)d_in[2];
  const float* sph = (const float*)d_in[3];
  const float* Wq = (const float*)d_in[4];
  const float* Wk = (const float*)d_in[5];
  const float* Wv = (const float*)d_in[6];
  const float* Wo = (const float*)d_in[7];
  const float* gamma = (const float*)d_in[8];
  const float* beta = (const float*)d_in[9];

  float* out = (float*)d_out;                 // [S,B,D]
  float* P = out + (size_t)4 * 1024 * 1024;   // [B,H,S,S]

  char* ws = (char*)d_ws;
  __hip_bfloat16* wqb = (__hip_bfloat16*)(ws + ((size_t)24 << 20));  // 2MB
  __hip_bfloat16* wkb = (__hip_bfloat16*)(ws + ((size_t)26 << 20));
  __hip_bfloat16* wvb = (__hip_bfloat16*)(ws + ((size_t)28 << 20));
  __hip_bfloat16* wob = (__hip_bfloat16*)(ws + ((size_t)30 << 20));
  __hip_bfloat16* Qh = (__hip_bfloat16*)(ws + ((size_t)32 << 20));   // 8MB [bh][s][dk]
  __hip_bfloat16* Khb = (__hip_bfloat16*)(ws + ((size_t)40 << 20));  // 8MB [bh][s][dk]
  __hip_bfloat16* VTb = (__hip_bfloat16*)(ws + ((size_t)48 << 20));  // 8MB [bh][dk][s]
  __hip_bfloat16* Ob = (__hip_bfloat16*)(ws + ((size_t)56 << 20));   // 8MB [B][S][D]
  float* Z = (float*)(ws + ((size_t)64 << 20));                      // 16MB [B][S][D]

  const dim3 blk(256);
  k_cvt4<<<4096, blk, 0, stream>>>(Wq, Wk, Wv, Wo, wqb, wkb, wvb, wob);

  k_proj3<<<dim3(32, 16, 3), blk, 0, stream>>>(q, k, v, wqb, wkb, wvb,
                                               Qh, Khb, VTb);

  k_attn<<<dim3(64, 64), blk, 0, stream>>>(Qh, Khb, VTb, sph, P, Ob);

  k_wo<<<dim3(32, 16), blk, 0, stream>>>(Ob, wob, q, Z);
  k_ln<<<4096, blk, 0, stream>>>(Z, gamma, beta, out);
}

// Round 19
// 243.290 us; speedup vs baseline: 1.0293x; 1.0293x over previous
//
#include <hip/hip_runtime.h>
#include <hip/hip_bf16.h>
#include <hip/hip_fp16.h>
#include <cstdint>

// Dims
constexpr int B_ = 4, H_ = 16, S_ = 1024, D_ = 1024, DK_ = 64;

typedef __bf16 bf16x8 __attribute__((ext_vector_type(8)));
typedef float f32x4 __attribute__((ext_vector_type(4)));
typedef __fp16 fp16x2 __attribute__((ext_vector_type(2)));
#define MFMA16(a, b, c) __builtin_amdgcn_mfma_f32_16x16x32_bf16(a, b, c, 0, 0, 0)

static __device__ inline unsigned short f2bf(float f) {
  __hip_bfloat16 h = __float2bfloat16(f);
  return *reinterpret_cast<unsigned short*>(&h);
}
static __device__ inline unsigned packbf(float lo, float hi) {
  return ((unsigned)f2bf(hi) << 16) | (unsigned)f2bf(lo);
}
static __device__ inline unsigned pack_f16(float x, float y) {
  fp16x2 p = __builtin_amdgcn_cvt_pkrtz(x, y);  // 1 instruction
  return *reinterpret_cast<unsigned*>(&p);
}
static __device__ inline float f16lo(unsigned u) {
  unsigned short s = (unsigned short)(u & 0xffff);
  return __half2float(*reinterpret_cast<__half*>(&s));
}
static __device__ inline float f16hi(unsigned u) {
  unsigned short s = (unsigned short)(u >> 16);
  return __half2float(*reinterpret_cast<__half*>(&s));
}
static __device__ inline float bf2f(unsigned short u) {
  const unsigned v = ((unsigned)u) << 16;
  return *reinterpret_cast<const float*>(&v);
}

// ---------------------------------------------------------------------------
// Single fused f32->bf16 conversion for all 7 tensors (q,k,v + 4 weights).
// ---------------------------------------------------------------------------
__global__ __launch_bounds__(256) void k_cvt7(const float* __restrict__ x0,
                                              const float* __restrict__ x1,
                                              const float* __restrict__ x2,
                                              const float* __restrict__ w0,
                                              const float* __restrict__ w1,
                                              const float* __restrict__ w2,
                                              const float* __restrict__ w3,
                                              __hip_bfloat16* __restrict__ y0,
                                              __hip_bfloat16* __restrict__ y1,
                                              __hip_bfloat16* __restrict__ y2,
                                              __hip_bfloat16* __restrict__ z0,
                                              __hip_bfloat16* __restrict__ z1,
                                              __hip_bfloat16* __restrict__ z2,
                                              __hip_bfloat16* __restrict__ z3) {
  const float* x;
  __hip_bfloat16* y;
  int i;
  if (blockIdx.x < 12288) {
    const int sel = blockIdx.x >> 12;
    i = (blockIdx.x & 4095) * 256 + threadIdx.x;
    x = sel == 0 ? x0 : (sel == 1 ? x1 : x2);
    y = sel == 0 ? y0 : (sel == 1 ? y1 : y2);
  } else {
    const int wid = blockIdx.x - 12288;
    const int sel = wid >> 10;
    i = (wid & 1023) * 256 + threadIdx.x;
    x = sel == 0 ? w0 : (sel == 1 ? w1 : (sel == 2 ? w2 : w3));
    y = sel == 0 ? z0 : (sel == 1 ? z1 : (sel == 2 ? z2 : z3));
  }
  const float4 v = reinterpret_cast<const float4*>(x)[i];
  ushort4 o;
  o.x = f2bf(v.x); o.y = f2bf(v.y); o.z = f2bf(v.z); o.w = f2bf(v.w);
  *reinterpret_cast<ushort4*>(&y[(size_t)i * 4]) = o;
}

// ---------------------------------------------------------------------------
// Fused Q/K/V projections (bf16 in, 128x64 tile, R17-proven).
// blockIdx.z selects tensor; z==2 (V) writes transposed. 1536 blocks.
// ---------------------------------------------------------------------------
__global__ __launch_bounds__(256) void k_proj3(const __hip_bfloat16* __restrict__ xq,
                                               const __hip_bfloat16* __restrict__ xk,
                                               const __hip_bfloat16* __restrict__ xv,
                                               const __hip_bfloat16* __restrict__ wq,
                                               const __hip_bfloat16* __restrict__ wk,
                                               const __hip_bfloat16* __restrict__ wv,
                                               __hip_bfloat16* __restrict__ Qh,
                                               __hip_bfloat16* __restrict__ Kh,
                                               __hip_bfloat16* __restrict__ VT) {
  __shared__ __hip_bfloat16 Als[128 * 64];
  __shared__ __hip_bfloat16 Bls[64 * 64];
  const int z = blockIdx.z;
  const __hip_bfloat16* A = z == 0 ? xq : (z == 1 ? xk : xv);
  const __hip_bfloat16* Bw = z == 0 ? wq : (z == 1 ? wk : wv);
  __hip_bfloat16* Yb = z == 0 ? Qh : (z == 1 ? Kh : VT);
  const int rt = blockIdx.x, ct = blockIdx.y;
  const int tid = threadIdx.x;
  const int lane = tid & 63;
  const int l15 = lane & 15, g = lane >> 4;
  const int w = tid >> 6;
  const int wr = w >> 1, wc = w & 1;
  f32x4 acc[4][2] = {};

  for (int k0 = 0; k0 < D_; k0 += 64) {
#pragma unroll
    for (int q = 0; q < 4; ++q) {
      const int slot0 = q * 256 + (tid & 192);
      const int slot = slot0 + lane;
      const int r = slot >> 3, p = slot & 7;
      const int lc = p ^ (r & 7);
      const __hip_bfloat16* src = A + (size_t)(rt * 128 + r) * D_ + k0 + lc * 8;
      __builtin_amdgcn_global_load_lds(
          (const __attribute__((address_space(1))) unsigned int*)src,
          (__attribute__((address_space(3))) unsigned int*)&Als[slot0 * 8], 16, 0, 0);
    }
#pragma unroll
    for (int q = 0; q < 2; ++q) {
      const int slot0 = q * 256 + (tid & 192);
      const int slot = slot0 + lane;
      const int r = slot >> 3, p = slot & 7;
      const int lc = p ^ (r & 7);
      const __hip_bfloat16* src = Bw + (size_t)(ct * 64 + r) * D_ + k0 + lc * 8;
      __builtin_amdgcn_global_load_lds(
          (const __attribute__((address_space(1))) unsigned int*)src,
          (__attribute__((address_space(3))) unsigned int*)&Bls[slot0 * 8], 16, 0, 0);
    }
    __syncthreads();
#pragma unroll
    for (int ks = 0; ks < 2; ++ks) {
      bf16x8 bfr[2];
#pragma unroll
      for (int cf = 0; cf < 2; ++cf) {
        const int r = wc * 32 + cf * 16 + l15;
        const int p = (ks * 4 + g) ^ (r & 7);
        bfr[cf] = *reinterpret_cast<const bf16x8*>(&Bls[(r * 8 + p) * 8]);
      }
#pragma unroll
      for (int fi = 0; fi < 4; ++fi) {
        const int r = wr * 64 + fi * 16 + l15;
        const int p = (ks * 4 + g) ^ (r & 7);
        const bf16x8 af = *reinterpret_cast<const bf16x8*>(&Als[(r * 8 + p) * 8]);
        acc[fi][0] = MFMA16(af, bfr[0], acc[fi][0]);
        acc[fi][1] = MFMA16(af, bfr[1], acc[fi][1]);
      }
    }
    __syncthreads();
  }
#pragma unroll
  for (int fi = 0; fi < 4; ++fi)
#pragma unroll
    for (int cf = 0; cf < 2; ++cf)
#pragma unroll
      for (int r = 0; r < 4; ++r) {
        const int m = rt * 128 + wr * 64 + fi * 16 + 4 * g + r;
        const int t = wc * 32 + cf * 16 + l15;
        const float val = acc[fi][cf][r];
        const int s = m >> 2, b = m & 3;
        if (z != 2) {
          Yb[((size_t)((b * H_ + ct) * S_ + s)) * DK_ + t] = __float2bfloat16(val);
        } else {
          Yb[((size_t)((b * H_ + ct) * DK_ + t)) * S_ + s] = __float2bfloat16(val);
        }
      }
}

// ---------------------------------------------------------------------------
// Wo GEMM + residual -> bf16 Z. 64x64 tile -> grid (64,16) = 1024 blocks
// (4 blocks/CU; the 128-tile version ran 512 blocks = 2/CU, latency-starved).
// ---------------------------------------------------------------------------
__global__ __launch_bounds__(256) void k_wo(const __hip_bfloat16* __restrict__ A,
                                            const __hip_bfloat16* __restrict__ Bw,
                                            const float* __restrict__ resid,
                                            __hip_bfloat16* __restrict__ Zb) {
  __shared__ __hip_bfloat16 Als[64 * 64];
  __shared__ __hip_bfloat16 Bls[64 * 64];
  const int rt = blockIdx.x, ct = blockIdx.y;
  const int tid = threadIdx.x;
  const int lane = tid & 63;
  const int l15 = lane & 15, g = lane >> 4;
  const int w = tid >> 6;
  const int wr = w >> 1, wc = w & 1;
  f32x4 acc[2][2] = {};
  for (int k0 = 0; k0 < D_; k0 += 64) {
#pragma unroll
    for (int q = 0; q < 2; ++q) {
      const int slot0 = q * 256 + (tid & 192);
      const int slot = slot0 + lane;
      const int r = slot >> 3, p = slot & 7;
      const int lc = p ^ (r & 7);
      const __hip_bfloat16* src = A + (size_t)(rt * 64 + r) * D_ + k0 + lc * 8;
      __builtin_amdgcn_global_load_lds(
          (const __attribute__((address_space(1))) unsigned int*)src,
          (__attribute__((address_space(3))) unsigned int*)&Als[slot0 * 8], 16, 0, 0);
    }
#pragma unroll
    for (int q = 0; q < 2; ++q) {
      const int slot0 = q * 256 + (tid & 192);
      const int slot = slot0 + lane;
      const int r = slot >> 3, p = slot & 7;
      const int lc = p ^ (r & 7);
      const __hip_bfloat16* src = Bw + (size_t)(ct * 64 + r) * D_ + k0 + lc * 8;
      __builtin_amdgcn_global_load_lds(
          (const __attribute__((address_space(1))) unsigned int*)src,
          (__attribute__((address_space(3))) unsigned int*)&Bls[slot0 * 8], 16, 0, 0);
    }
    __syncthreads();
#pragma unroll
    for (int ks = 0; ks < 2; ++ks) {
      bf16x8 bfr[2];
#pragma unroll
      for (int cf = 0; cf < 2; ++cf) {
        const int r = wc * 32 + cf * 16 + l15;
        const int p = (ks * 4 + g) ^ (r & 7);
        bfr[cf] = *reinterpret_cast<const bf16x8*>(&Bls[(r * 8 + p) * 8]);
      }
#pragma unroll
      for (int fi = 0; fi < 2; ++fi) {
        const int r = wr * 32 + fi * 16 + l15;
        const int p = (ks * 4 + g) ^ (r & 7);
        const bf16x8 af = *reinterpret_cast<const bf16x8*>(&Als[(r * 8 + p) * 8]);
        acc[fi][0] = MFMA16(af, bfr[0], acc[fi][0]);
        acc[fi][1] = MFMA16(af, bfr[1], acc[fi][1]);
      }
    }
    __syncthreads();
  }
#pragma unroll
  for (int fi = 0; fi < 2; ++fi)
#pragma unroll
    for (int cf = 0; cf < 2; ++cf)
#pragma unroll
      for (int r = 0; r < 4; ++r) {
        const int m = rt * 64 + wr * 32 + fi * 16 + 4 * g + r;
        const int t = wc * 32 + cf * 16 + l15;
        const int b = m >> 10, s = m & 1023;
        const int o = ct * 64 + t;
        const float val =
            acc[fi][cf][r] + resid[(size_t)(s * B_ + b) * D_ + o];
        Zb[(size_t)m * D_ + o] = __float2bfloat16(val);
      }
}

// ---------------------------------------------------------------------------
// Fused attention (R16/R17-proven: 165us — nontemporal sph/P streams, no-max
// softmax, deferred normalization, 2-deep K pipeline). UNCHANGED.
// ---------------------------------------------------------------------------
__global__ __launch_bounds__(256, 4) void k_attn(const __hip_bfloat16* __restrict__ Qh,
                                                 const __hip_bfloat16* __restrict__ Kh,
                                                 const __hip_bfloat16* __restrict__ VT,
                                                 const float* __restrict__ sph,
                                                 float* __restrict__ Pout,
                                                 __hip_bfloat16* __restrict__ O) {
  __shared__ unsigned int Plds[16 * 512];  // 32KB logits/P (f16/bf16 pairs)
  __shared__ float invl[16];               // per-row 1/sum for phase 3
  const int tid = threadIdx.x, lane = tid & 63, w = tid >> 6;
  const int l15 = lane & 15, g = lane >> 4;
  const int it = blockIdx.x, bh = blockIdx.y;
  const unsigned sw = (unsigned)((l15 & 7) << 2);
  const int wrow = w * 4;
  constexpr float kScale = 0.125f * 1.44269504088896f;  // /8 then log2(e)

  // ---- phase 1: raw logits; 2-deep K pipeline ----
  {
    const __hip_bfloat16* qp = Qh + ((size_t)bh * S_ + it * 16 + l15) * DK_ + 8 * g;
    const bf16x8 qf0 = *reinterpret_cast<const bf16x8*>(qp);
    const bf16x8 qf1 = *reinterpret_cast<const bf16x8*>(qp + 32);
    const __hip_bfloat16* kb0 =
        Kh + (size_t)bh * S_ * DK_ + (size_t)(w * 256 + l15) * DK_ + 8 * g;
    bf16x8 kra[2], krb[2], krc[2], krd[2];
    kra[0] = *reinterpret_cast<const bf16x8*>(kb0);
    krb[0] = *reinterpret_cast<const bf16x8*>(kb0 + 32);
    krc[0] = *reinterpret_cast<const bf16x8*>(kb0 + 16 * DK_);
    krd[0] = *reinterpret_cast<const bf16x8*>(kb0 + 16 * DK_ + 32);
#pragma unroll
    for (int j = 0; j < 8; ++j) {
      const int cur = j & 1, nxt = cur ^ 1;
      if (j < 7) {
        const __hip_bfloat16* kp = kb0 + (size_t)(j + 1) * 32 * DK_;
        kra[nxt] = *reinterpret_cast<const bf16x8*>(kp);
        krb[nxt] = *reinterpret_cast<const bf16x8*>(kp + 32);
        krc[nxt] = *reinterpret_cast<const bf16x8*>(kp + 16 * DK_);
        krd[nxt] = *reinterpret_cast<const bf16x8*>(kp + 16 * DK_ + 32);
      }
      f32x4 a0 = {0.f, 0.f, 0.f, 0.f};
      f32x4 a1 = {0.f, 0.f, 0.f, 0.f};
      __builtin_amdgcn_s_setprio(1);
      a0 = MFMA16(kra[cur], qf0, a0);
      a0 = MFMA16(krb[cur], qf1, a0);
      a1 = MFMA16(krc[cur], qf0, a1);
      a1 = MFMA16(krd[cur], qf1, a1);
      __builtin_amdgcn_s_setprio(0);
      const int key0 = w * 256 + j * 32;
      uint2 u0, u1;
      u0.x = pack_f16(a0[0] * kScale, a0[1] * kScale);
      u0.y = pack_f16(a0[2] * kScale, a0[3] * kScale);
      u1.x = pack_f16(a1[0] * kScale, a1[1] * kScale);
      u1.y = pack_f16(a1[2] * kScale, a1[3] * kScale);
      const int base0 = l15 * 512 + (key0 >> 1) + 2 * g;  // pair index
      *reinterpret_cast<uint2*>(&Plds[(unsigned)base0 ^ sw]) = u0;
      *reinterpret_cast<uint2*>(&Plds[(unsigned)(base0 + 8) ^ sw]) = u1;
    }
  }
  __syncthreads();

  // ---- phase 2: per-row; no-max softmax, deferred normalization ----
  {
    const f32x4* sbase = reinterpret_cast<const f32x4*>(
        sph + ((size_t)bh << 20) + (((size_t)(it * 16)) << 10));
#pragma unroll
    for (int rr = 0; rr < 4; ++rr) {
      const int row = wrow + rr;
      const unsigned rsw = (unsigned)((row & 7) << 2);
      const int lbase = row * 512;
      uint2 uv[4];
      f32x4 sv[4];
#pragma unroll
      for (int i = 0; i < 4; ++i) {
        sv[i] = __builtin_nontemporal_load(&sbase[(size_t)row * 256 + lane + 64 * i]);
        uv[i] = *reinterpret_cast<uint2*>(
            &Plds[(unsigned)(lbase + 2 * lane + 128 * i) ^ rsw]);
      }
      float va[16];
#pragma unroll
      for (int i = 0; i < 4; ++i) {
        va[4 * i + 0] = f16lo(uv[i].x) * sv[i][0];
        va[4 * i + 1] = f16hi(uv[i].x) * sv[i][1];
        va[4 * i + 2] = f16lo(uv[i].y) * sv[i][2];
        va[4 * i + 3] = f16hi(uv[i].y) * sv[i][3];
      }
#pragma unroll
      for (int i = 0; i < 16; ++i) va[i] = exp2f(fminf(va[i], 60.f));
#pragma unroll
      for (int i = 0; i < 4; ++i) {
        uint2 pb;
        pb.x = packbf(va[4 * i + 0], va[4 * i + 1]);
        pb.y = packbf(va[4 * i + 2], va[4 * i + 3]);
        *reinterpret_cast<uint2*>(
            &Plds[(unsigned)(lbase + 2 * lane + 128 * i) ^ rsw]) = pb;
      }
      const float b0 = va[0] + va[1], b1 = va[2] + va[3], b2 = va[4] + va[5],
                  b3 = va[6] + va[7], b4 = va[8] + va[9], b5 = va[10] + va[11],
                  b6 = va[12] + va[13], b7 = va[14] + va[15];
      float sum = ((b0 + b1) + (b2 + b3)) + ((b4 + b5) + (b6 + b7));
#pragma unroll
      for (int off = 1; off < 64; off <<= 1) sum += __shfl_xor(sum, off);
      const float inv = 1.f / sum;
      if (lane == 0) invl[row] = inv;
      f32x4* po = reinterpret_cast<f32x4*>(Pout + ((size_t)bh << 20) +
                                           (((size_t)(it * 16 + row)) << 10));
#pragma unroll
      for (int i = 0; i < 4; ++i) {
        f32x4 p;
        p[0] = va[4 * i + 0] * inv;
        p[1] = va[4 * i + 1] * inv;
        p[2] = va[4 * i + 2] * inv;
        p[3] = va[4 * i + 3] * inv;
        __builtin_nontemporal_store(p, &po[lane + 64 * i]);
      }
    }
  }
  __syncthreads();

  // ---- phase 3: PV on unnormalized P, batches of 8; scale by invl[row] ----
  {
    const int c0 = w * 16;
    f32x4 o0 = {0.f, 0.f, 0.f, 0.f};
    const __hip_bfloat16* vb =
        VT + (size_t)bh * DK_ * S_ + (size_t)(c0 + l15) * S_ + 8 * g;
#pragma unroll
    for (int kb2 = 0; kb2 < 4; ++kb2) {
      bf16x8 vreg[8];
      bf16x8 preg[8];
#pragma unroll
      for (int u = 0; u < 8; ++u)
        vreg[u] = *reinterpret_cast<const bf16x8*>(vb + kb2 * 256 + u * 32);
#pragma unroll
      for (int u = 0; u < 8; ++u) {
        const int k0 = kb2 * 256 + u * 32;
        preg[u] = *reinterpret_cast<const bf16x8*>(
            &Plds[(unsigned)(l15 * 512 + (k0 >> 1) + 4 * g) ^ sw]);
      }
      __builtin_amdgcn_s_setprio(1);
#pragma unroll
      for (int u = 0; u < 8; ++u) o0 = MFMA16(preg[u], vreg[u], o0);
      __builtin_amdgcn_s_setprio(0);
    }
    const int b = bh >> 4, h = bh & 15;
    const float iv0 = invl[4 * g + 0], iv1 = invl[4 * g + 1];
    const float iv2 = invl[4 * g + 2], iv3 = invl[4 * g + 3];
    const float ivr[4] = {iv0, iv1, iv2, iv3};
#pragma unroll
    for (int r = 0; r < 4; ++r) {
      const int srow = it * 16 + 4 * g + r;
      O[((size_t)(b * S_ + srow)) * D_ + h * DK_ + c0 + l15] =
          __float2bfloat16(o0[r] * ivr[r]);
    }
  }
}

// ---------------------------------------------------------------------------
// LayerNorm over D from bf16 Z, write f32 [S,B,D]
// ---------------------------------------------------------------------------
__global__ __launch_bounds__(256) void k_ln(const __hip_bfloat16* __restrict__ Zb,
                                            const float* __restrict__ gamma,
                                            const float* __restrict__ beta,
                                            float* __restrict__ out) {
  const int r = blockIdx.x;  // b*S+s
  const int b = r >> 10, s = r & 1023;
  const int tid = threadIdx.x;
  const ushort4 zu = *reinterpret_cast<const ushort4*>(Zb + (size_t)r * D_ + (tid << 2));
  float4 z;
  z.x = bf2f(zu.x); z.y = bf2f(zu.y); z.z = bf2f(zu.z); z.w = bf2f(zu.w);
  float sum = z.x + z.y + z.z + z.w;
  float sq = z.x * z.x + z.y * z.y + z.z * z.z + z.w * z.w;
#pragma unroll
  for (int off = 1; off < 64; off <<= 1) {
    sum += __shfl_xor(sum, off);
    sq += __shfl_xor(sq, off);
  }
  __shared__ float rs[4];
  __shared__ float rq[4];
  const int wv = tid >> 6, ln = tid & 63;
  if (ln == 0) { rs[wv] = sum; rq[wv] = sq; }
  __syncthreads();
  const float tsum = rs[0] + rs[1] + rs[2] + rs[3];
  const float tsq = rq[0] + rq[1] + rq[2] + rq[3];
  const float mu = tsum * (1.0f / 1024.0f);
  const float var = tsq * (1.0f / 1024.0f) - mu * mu;
  const float rstd = rsqrtf(var + 1e-6f);
  const float4 gm = *reinterpret_cast<const float4*>(gamma + (tid << 2));
  const float4 bt = *reinterpret_cast<const float4*>(beta + (tid << 2));
  float4 o;
  o.x = (z.x - mu) * rstd * gm.x + bt.x;
  o.y = (z.y - mu) * rstd * gm.y + bt.y;
  o.z = (z.z - mu) * rstd * gm.z + bt.z;
  o.w = (z.w - mu) * rstd * gm.w + bt.w;
  *reinterpret_cast<float4*>(out + (size_t)(s * B_ + b) * D_ + (tid << 2)) = o;
}

extern "C" void kernel_launch(void* const* d_in, const int* in_sizes, int n_in,
                              void* d_out, int out_size, void* d_ws, size_t ws_size,
                              hipStream_t stream) {
  const float* q = (const float*)d_in[0];
  const float* k = (const float*)d_in[1];
  const float* v = (const float*)d_in[2];
  const float* sph = (const float*)d_in[3];
  const float* Wq = (const float*)d_in[4];
  const float* Wk = (const float*)d_in[5];
  const float* Wv = (const float*)d_in[6];
  const float* Wo = (const float*)d_in[7];
  const float* gamma = (const float*)d_in[8];
  const float* beta = (const float*)d_in[9];

  float* out = (float*)d_out;                 // [S,B,D]
  float* P = out + (size_t)4 * 1024 * 1024;   // [B,H,S,S]

  char* ws = (char*)d_ws;
  __hip_bfloat16* xq = (__hip_bfloat16*)(ws);                        // 8MB [S*B][D]
  __hip_bfloat16* xk = (__hip_bfloat16*)(ws + ((size_t)8 << 20));    // 8MB
  __hip_bfloat16* xv = (__hip_bfloat16*)(ws + ((size_t)16 << 20));   // 8MB
  __hip_bfloat16* wqb = (__hip_bfloat16*)(ws + ((size_t)24 << 20));  // 2MB
  __hip_bfloat16* wkb = (__hip_bfloat16*)(ws + ((size_t)26 << 20));
  __hip_bfloat16* wvb = (__hip_bfloat16*)(ws + ((size_t)28 << 20));
  __hip_bfloat16* wob = (__hip_bfloat16*)(ws + ((size_t)30 << 20));
  __hip_bfloat16* Qh = (__hip_bfloat16*)(ws + ((size_t)32 << 20));   // 8MB [bh][s][dk]
  __hip_bfloat16* Khb = (__hip_bfloat16*)(ws + ((size_t)40 << 20));  // 8MB [bh][s][dk]
  __hip_bfloat16* VTb = (__hip_bfloat16*)(ws + ((size_t)48 << 20));  // 8MB [bh][dk][s]
  __hip_bfloat16* Ob = (__hip_bfloat16*)(ws + ((size_t)56 << 20));   // 8MB [B][S][D]
  __hip_bfloat16* Zb = (__hip_bfloat16*)(ws + ((size_t)64 << 20));   // 8MB [B][S][D]

  const dim3 blk(256);
  k_cvt7<<<16384, blk, 0, stream>>>(q, k, v, Wq, Wk, Wv, Wo,
                                    xq, xk, xv, wqb, wkb, wvb, wob);

  k_proj3<<<dim3(32, 16, 3), blk, 0, stream>>>(xq, xk, xv, wqb, wkb, wvb,
                                               Qh, Khb, VTb);

  k_attn<<<dim3(64, 64), blk, 0, stream>>>(Qh, Khb, VTb, sph, P, Ob);

  k_wo<<<dim3(64, 16), blk, 0, stream>>>(Ob, wob, q, Zb);
  k_ln<<<4096, blk, 0, stream>>>(Zb, gamma, beta, out);
}